// Round 1
// baseline (1622.291 us; speedup 1.0000x reference)
//
#include <hip/hip_runtime.h>
#include <stdint.h>

// ---------------- types ----------------
typedef _Float16 half_t;
typedef _Float16 half8 __attribute__((ext_vector_type(8)));
typedef _Float16 half4 __attribute__((ext_vector_type(4)));
typedef float f32x16 __attribute__((ext_vector_type(16)));
typedef float f32x4  __attribute__((ext_vector_type(4)));

// ---------------- problem constants ----------------
#define OBS_D 128
#define ACT_D 32
#define IN_D  160            // OBS_D + ACT_D
#define H_D   512
#define T_H   63             // horizon
#define NROWS 2048           // B*N = 32*64
#define KTOT  672            // IN_D + H_D
#define KT_ALL 42            // KTOT/16
#define KT_X   10            // IN_D/16
#define NT_ALL 48            // 1536/32
#define RB     32            // rows per block in recurrent kernel
#define NBLK   64            // NROWS/RB
#define PRED_ELEMS (NROWS*T_H*OBS_D)   // 16515072 ; hs starts here in d_out

#define ZERO16 {0.f,0.f,0.f,0.f,0.f,0.f,0.f,0.f,0.f,0.f,0.f,0.f,0.f,0.f,0.f,0.f}
#define MFMA16 __builtin_amdgcn_mfma_f32_32x32x16_f16

__device__ __forceinline__ float sigm(float x) {
    return __builtin_amdgcn_rcpf(1.0f + __expf(-x));
}
__device__ __forceinline__ float tanh_f(float x) {
    // robust for large |x|: expf->inf -> rcp->0 -> -1 ; expf->0 -> 2-1 = +1
    return 2.0f * __builtin_amdgcn_rcpf(1.0f + __expf(-2.0f * x)) - 1.0f;
}

// ============================================================================
// pack_w: W = [w_ih | w_hh] (gates x 672) and w_dec (128 x 512) -> fp16
// B-fragment order for mfma_32x32x16: frag[nt][kt][lane][j] = W[n][k],
//   n = nt*32 + (lane&31), k = kt*16 + (lane>>5)*8 + j
// threads: 48*42*64 = 129024 (gates) + 4*32*64 = 8192 (dec) = 137216 = 536*256
// ============================================================================
__global__ void pack_w(const float* __restrict__ w_ih, const float* __restrict__ w_hh,
                       const float* __restrict__ w_dec,
                       half_t* __restrict__ wpack, half_t* __restrict__ wdpack) {
    int idx = blockIdx.x * 256 + threadIdx.x;
    int lane = idx & 63;
    int m = lane & 31;
    int khalf = lane >> 5;
    if (idx < NT_ALL * KT_ALL * 64) {
        int kt = (idx >> 6) % KT_ALL;
        int nt = idx / (64 * KT_ALL);
        int n = nt * 32 + m;
        int k0 = kt * 16 + khalf * 8;
        half8 o;
        #pragma unroll
        for (int j = 0; j < 8; ++j) {
            int k = k0 + j;
            float v = (k < IN_D) ? w_ih[(size_t)n * IN_D + k]
                                 : w_hh[(size_t)n * H_D + (k - IN_D)];
            o[j] = (half_t)v;
        }
        *(half8*)(wpack + (size_t)idx * 8) = o;
    } else {
        int r = idx - NT_ALL * KT_ALL * 64;   // < 8192 (offset is multiple of 64)
        int kt = (r >> 6) % 32;
        int nt = r / (64 * 32);
        int n = nt * 32 + m;                  // output col (0..127)
        int k0 = kt * 16 + khalf * 8;
        half8 o;
        #pragma unroll
        for (int j = 0; j < 8; ++j) o[j] = (half_t)w_dec[(size_t)n * H_D + k0 + j];
        *(half8*)(wdpack + (size_t)r * 8) = o;
    }
}

// ============================================================================
// pack_x: x = concat(obs, act) -> fp16 A-fragment order
// xfrag[rb][t][kt][lane][j] = x[t][row][k], row = rb*32 + (lane&31),
//   k = kt*16 + (lane>>5)*8 + j
// threads: 64*63*10*64 = 2580480 = 10080*256 (exact)
// ============================================================================
__global__ void pack_x(const float* __restrict__ obs, const float* __restrict__ act,
                       half_t* __restrict__ xfrag) {
    int idx = blockIdx.x * 256 + threadIdx.x;
    int lane = idx & 63;
    int kt = (idx >> 6) % KT_X;
    int t  = (idx / (64 * KT_X)) % T_H;
    int rb = idx / (64 * KT_X * T_H);
    int m = lane & 31;
    int row = rb * RB + m;
    int b = row >> 6, nn = row & 63;
    int k0 = kt * 16 + (lane >> 5) * 8;
    const float* ob = obs + (((size_t)(b * 64 + t)) * 64 + nn) * OBS_D;  // T=64 in input!
    const float* ac = act + (((size_t)(b * 64 + t)) * 64 + nn) * ACT_D;
    half8 o;
    #pragma unroll
    for (int j = 0; j < 8; ++j) {
        int k = k0 + j;
        float v = (k < OBS_D) ? ob[k] : ac[k - OBS_D];
        o[j] = (half_t)v;
    }
    *(half8*)(xfrag + (size_t)idx * 8) = o;
}

// ============================================================================
// gru_main: 64 blocks x 512 threads (8 waves). Block rb owns rows rb*32..+32.
// Wave w owns h-dims [w*64, w*64+64) = n-tiles {2w,2w+1} of r, z, n gates.
// Gate GEMM: [x|h] (32x672, fp16, LDS A-frags) @ Wpack (B-frags from L2).
// r,z merge K fully; n-gate keeps gi (kt<10) and gh (kt>=10) separate:
//   n = tanh(gi_n + b_ihn + r*(gh_n + b_hhn)).
// h kept fp32 in registers (C/D layout), scattered to LDS as fp16 A-frags.
// ============================================================================
__global__ __launch_bounds__(512, 2) void gru_main(
        const half_t* __restrict__ wpack, const half_t* __restrict__ xfrag,
        const float* __restrict__ b_ih, const float* __restrict__ b_hh,
        float* __restrict__ out) {
    __shared__ __align__(16) half_t Abuf[KT_ALL * 64 * 8];   // 43008 B

    const int tid = threadIdx.x;
    const int w = tid >> 6;
    const int lane = tid & 63;
    const int col = lane & 31;
    const int khalf = lane >> 5;
    const int mbase = khalf * 4;
    const int rb = blockIdx.x;

    // ---- init: zero h-part of Abuf, copy x(t=0) into x-part ----
    for (int i = tid; i < (KT_ALL - KT_X) * 64 * 8; i += 512)
        Abuf[KT_X * 64 * 8 + i] = (half_t)0.0f;
    {
        const uint4* src = (const uint4*)(xfrag + (size_t)rb * T_H * (KT_X * 512));
        uint4* dst = (uint4*)Abuf;
        for (int s = tid; s < KT_X * 64; s += 512) dst[s] = src[s];
    }

    // ---- per-lane constants ----
    const int d0 = (2 * w) * 32 + col;       // wave's dim, tile 0
    const int d1 = d0 + 32;                  // tile 1
    const float br0 = b_ih[d0] + b_hh[d0];
    const float br1 = b_ih[d1] + b_hh[d1];
    const float bz0 = b_ih[512 + d0] + b_hh[512 + d0];
    const float bz1 = b_ih[512 + d1] + b_hh[512 + d1];
    const float bi0 = b_ih[1024 + d0];
    const float bi1 = b_ih[1024 + d1];
    const float bh0 = b_hh[1024 + d0];
    const float bh1 = b_hh[1024 + d1];

    // B-fragment stream bases (element offsets; +512 per kt)
    const half_t* wr0 = wpack + ((size_t)(2 * w)      * KT_ALL) * 512 + lane * 8;
    const half_t* wr1 = wpack + ((size_t)(2 * w + 1)  * KT_ALL) * 512 + lane * 8;
    const half_t* wz0 = wpack + ((size_t)(16 + 2 * w) * KT_ALL) * 512 + lane * 8;
    const half_t* wz1 = wpack + ((size_t)(17 + 2 * w) * KT_ALL) * 512 + lane * 8;
    const half_t* wn0 = wpack + ((size_t)(32 + 2 * w) * KT_ALL) * 512 + lane * 8;
    const half_t* wn1 = wpack + ((size_t)(33 + 2 * w) * KT_ALL) * 512 + lane * 8;

    const int b_out = rb >> 1;
    const int nn_base = (rb & 1) << 5;

    // h master (fp32) in C/D layout registers
    float h0[16], h1[16];
    #pragma unroll
    for (int i = 0; i < 16; ++i) { h0[i] = 0.0f; h1[i] = 0.0f; }

    // scatter-write constants (C/D reg -> A-frag LDS position)
    const int lp = 32 * ((col >> 3) & 1);
    const int jj = col & 7;
    const int ktb0 = KT_X + (2 * w) * 2 + (col >> 4);
    const int ktb1 = KT_X + (2 * w + 1) * 2 + (col >> 4);

    __syncthreads();

    for (int t = 0; t < T_H; ++t) {
        f32x16 ar0 = ZERO16, ar1 = ZERO16, az0 = ZERO16, az1 = ZERO16;
        f32x16 ai0 = ZERO16, ai1 = ZERO16, ah0 = ZERO16, ah1 = ZERO16;
        const half8* Af = (const half8*)Abuf + lane;

        #pragma unroll 2
        for (int kt = 0; kt < KT_X; ++kt) {           // x part: r, z, gi_n
            half8 a = Af[kt * 64];
            ar0 = MFMA16(a, *(const half8*)(wr0 + kt * 512), ar0, 0, 0, 0);
            ar1 = MFMA16(a, *(const half8*)(wr1 + kt * 512), ar1, 0, 0, 0);
            az0 = MFMA16(a, *(const half8*)(wz0 + kt * 512), az0, 0, 0, 0);
            az1 = MFMA16(a, *(const half8*)(wz1 + kt * 512), az1, 0, 0, 0);
            ai0 = MFMA16(a, *(const half8*)(wn0 + kt * 512), ai0, 0, 0, 0);
            ai1 = MFMA16(a, *(const half8*)(wn1 + kt * 512), ai1, 0, 0, 0);
        }
        #pragma unroll 2
        for (int kt = KT_X; kt < KT_ALL; ++kt) {      // h part: r, z, gh_n
            half8 a = Af[kt * 64];
            ar0 = MFMA16(a, *(const half8*)(wr0 + kt * 512), ar0, 0, 0, 0);
            ar1 = MFMA16(a, *(const half8*)(wr1 + kt * 512), ar1, 0, 0, 0);
            az0 = MFMA16(a, *(const half8*)(wz0 + kt * 512), az0, 0, 0, 0);
            az1 = MFMA16(a, *(const half8*)(wz1 + kt * 512), az1, 0, 0, 0);
            ah0 = MFMA16(a, *(const half8*)(wn0 + kt * 512), ah0, 0, 0, 0);
            ah1 = MFMA16(a, *(const half8*)(wn1 + kt * 512), ah1, 0, 0, 0);
        }

        // ---- epilogue: gates -> h update -> global hs store ----
        float* hsrow = out + (size_t)PRED_ELEMS + ((size_t)(b_out * T_H + t)) * (64 * 512);
        #pragma unroll
        for (int r = 0; r < 16; ++r) {
            int m = (r & 3) + 8 * (r >> 2) + mbase;   // C/D row (verified mapping)
            float rr0 = sigm(ar0[r] + br0);
            float zz0 = sigm(az0[r] + bz0);
            float nn0 = tanh_f(ai0[r] + bi0 + rr0 * (ah0[r] + bh0));
            float hv0 = (1.0f - zz0) * nn0 + zz0 * h0[r];
            h0[r] = hv0;
            float rr1 = sigm(ar1[r] + br1);
            float zz1 = sigm(az1[r] + bz1);
            float nn1 = tanh_f(ai1[r] + bi1 + rr1 * (ah1[r] + bh1));
            float hv1 = (1.0f - zz1) * nn1 + zz1 * h1[r];
            h1[r] = hv1;
            float* hp = hsrow + (size_t)(nn_base + m) * 512;
            hp[d0] = hv0;
            hp[d1] = hv1;
        }

        __syncthreads();   // everyone done reading Abuf for step t

        if (t < T_H - 1) {
            // scatter h (fp16) into A-frag layout (kt >= KT_X region)
            #pragma unroll
            for (int r = 0; r < 16; ++r) {
                int m = (r & 3) + 8 * (r >> 2) + mbase;
                Abuf[ktb0 * 512 + (m + lp) * 8 + jj] = (half_t)h0[r];
                Abuf[ktb1 * 512 + (m + lp) * 8 + jj] = (half_t)h1[r];
            }
            // copy x(t+1) into x-part
            const uint4* src = (const uint4*)(xfrag +
                ((size_t)rb * T_H + (t + 1)) * (size_t)(KT_X * 512));
            uint4* dst = (uint4*)Abuf;
            for (int s = tid; s < KT_X * 64; s += 512) dst[s] = src[s];
        }
        __syncthreads();   // writes visible before next GEMM
    }
}

// ============================================================================
// dec_k: preds = hs @ w_dec^T + b_dec.  4032 blocks x 256 threads (4 waves).
// Block: 32 rows; wave w: output cols [w*32, w*32+32).
// ============================================================================
#define DPAD 520   // fp16 row stride (pad 512 -> 520 to break 32-way LDS conflicts)
__global__ __launch_bounds__(256) void dec_k(
        const float* __restrict__ hs, const half_t* __restrict__ wdpack,
        const float* __restrict__ b_dec, float* __restrict__ preds) {
    __shared__ __align__(16) half_t Ab[32 * DPAD];   // 33280 B
    const int tid = threadIdx.x, w = tid >> 6, lane = tid & 63;
    const size_t row0 = (size_t)blockIdx.x * 32;

    // stage 32x512 fp32 -> fp16 row-major (padded) in LDS, coalesced
    const float* src = hs + row0 * 512;
    #pragma unroll
    for (int c = 0; c < 16; ++c) {
        int f = c * 1024 + tid * 4;
        f32x4 v = *(const f32x4*)(src + f);
        int m = f >> 9, colc = f & 511;
        half4 o;
        o[0] = (half_t)v[0]; o[1] = (half_t)v[1]; o[2] = (half_t)v[2]; o[3] = (half_t)v[3];
        *(half4*)(Ab + m * DPAD + colc) = o;
    }
    __syncthreads();

    f32x16 acc = ZERO16;
    const half_t* wd = wdpack + ((size_t)w * 32) * 512 + lane * 8;
    const int mA = lane & 31, k0 = (lane >> 5) * 8;
    #pragma unroll 4
    for (int kt = 0; kt < 32; ++kt) {
        half8 a = *(const half8*)(Ab + mA * DPAD + kt * 16 + k0);
        half8 b = *(const half8*)(wd + kt * 512);
        acc = MFMA16(a, b, acc, 0, 0, 0);
    }
    const int colD = w * 32 + (lane & 31);
    const float bd = b_dec[colD];
    #pragma unroll
    for (int r = 0; r < 16; ++r) {
        int m = (r & 3) + 8 * (r >> 2) + 4 * (lane >> 5);
        preds[(row0 + m) * 128 + colD] = acc[r] + bd;
    }
}

// ============================================================================
extern "C" void kernel_launch(void* const* d_in, const int* in_sizes, int n_in,
                              void* d_out, int out_size, void* d_ws, size_t ws_size,
                              hipStream_t stream) {
    const float* obs   = (const float*)d_in[0];
    const float* act   = (const float*)d_in[1];
    const float* w_ih  = (const float*)d_in[2];
    const float* w_hh  = (const float*)d_in[3];
    const float* b_ih  = (const float*)d_in[4];
    const float* b_hh  = (const float*)d_in[5];
    const float* w_dec = (const float*)d_in[6];
    const float* b_dec = (const float*)d_in[7];
    // d_in[8] = horizon (fixed 63; compiled in)
    float* out = (float*)d_out;

    // workspace layout (fp16 elements): wpack | wdpack | xfrag  ~= 41.5 MB
    half_t* wpack  = (half_t*)d_ws;                      // 48*42*512  = 1032192
    half_t* wdpack = wpack + (size_t)NT_ALL * KT_ALL * 512;  // 4*32*512 = 65536
    half_t* xfrag  = wdpack + (size_t)4 * 32 * 512;      // 64*63*5120 = 20643840

    hipLaunchKernelGGL(pack_w, dim3(536), dim3(256), 0, stream,
                       w_ih, w_hh, w_dec, wpack, wdpack);
    hipLaunchKernelGGL(pack_x, dim3(10080), dim3(256), 0, stream, obs, act, xfrag);
    hipLaunchKernelGGL(gru_main, dim3(NBLK), dim3(512), 0, stream,
                       wpack, xfrag, b_ih, b_hh, out);
    hipLaunchKernelGGL(dec_k, dim3(NROWS * T_H / 32), dim3(256), 0, stream,
                       out + (size_t)PRED_ELEMS, wdpack, b_dec, out);
}